// Round 4
// baseline (146.298 us; speedup 1.0000x reference)
//
#include <hip/hip_runtime.h>
#include <math.h>

// RiemannianMetric: g[b,s,i,j] = sum_r tanh(x[b,s]·W[r]+b[r])^2 * A[r,i]*A[r,j] + lam*I
// B=2 S=1024 DIM=256 RANK=32. Output 512 MiB f32 -> store-BW floor ~80us @6.7TB/s.
// R3: LDS row-broadcast (per-CU shared pipe, ~82us) replaced by v_readlane from the
// wave's own column registers. Fold sqrt(w_r)=|tanh| into aj so BOTH operands come
// from one register set: (u_r A_ri)(u_r A_rj) = w_r A_ri A_rj. Main loop: 0 LDS ops.

constexpr int DIM  = 256;
constexpr int RANK = 32;

typedef float f32x4 __attribute__((ext_vector_type(4)));

static __device__ __forceinline__ float readlane_f32(float v, int lane) {
    return __builtin_bit_cast(float,
        __builtin_amdgcn_readlane(__builtin_bit_cast(int, v), lane));
}

__global__ __launch_bounds__(256, 2) void riemannian_metric_kernel(
    const float* __restrict__ x,          // [B*S, DIM]
    const float* __restrict__ A,          // [RANK, DIM]
    const float* __restrict__ log_lambda, // [1]
    const float* __restrict__ W,          // [RANK, DIM]
    const float* __restrict__ bvec,       // [RANK]
    float* __restrict__ out)              // [B*S, DIM, DIM]
{
    __shared__ float xs[DIM];
    __shared__ float sw[RANK];            // |tanh(x·W_r + b_r)|

    const int tid = threadIdx.x;
    const int pos = blockIdx.x;
    const int cg  = tid & 63;  // lane: owns columns 4cg..4cg+3
    const int rs  = tid >> 6;  // wave: owns rows 64rs..64rs+63
    const int j0  = cg * 4;

    // A-column loads first: independent of LDS/barriers, A is L2-resident (32KB)
    f32x4 aj[RANK];
    #pragma unroll
    for (int r = 0; r < RANK; ++r)
        aj[r] = *(const f32x4*)(A + r * DIM + j0);

    xs[tid] = x[(size_t)pos * DIM + tid];
    __syncthreads();

    // sw[r] = |tanh(x·W[r]+b[r])| — 8 lanes per rank, shfl-reduced
    {
        const int r = tid >> 3, seg = tid & 7;
        const f32x4* wr4 = (const f32x4*)(W + r * DIM + seg * 32);
        const f32x4* xr4 = (const f32x4*)(xs + seg * 32);
        float dot = 0.f;
        #pragma unroll
        for (int q = 0; q < 8; ++q) {
            f32x4 wv = wr4[q], xv = xr4[q];
            dot = fmaf(wv.x, xv.x, dot);
            dot = fmaf(wv.y, xv.y, dot);
            dot = fmaf(wv.z, xv.z, dot);
            dot = fmaf(wv.w, xv.w, dot);
        }
        dot += __shfl_xor(dot, 1);
        dot += __shfl_xor(dot, 2);
        dot += __shfl_xor(dot, 4);
        if (seg == 0) sw[r] = fabsf(tanhf(dot + bvec[r]));
    }
    __syncthreads();

    // fold u_r = sqrt(w_r) into the column registers
    #pragma unroll
    for (int r = 0; r < RANK; ++r)
        aj[r] *= sw[r]; // wave-uniform LDS broadcast (prologue only)

    const float lam = expf(log_lambda[0]);
    f32x4* op = (f32x4*)(out + (size_t)pos * DIM * DIM + (size_t)(rs * 64) * DIM + j0);

    // rows i = rs*64 + kb*4 + c; row operand u_r*A[r][i] = readlane(aj[r][c], rs*16+kb)
    #pragma unroll 1
    for (int kb = 0; kb < 16; ++kb) {
        const int lane = rs * 16 + kb; // wave-uniform
        #pragma unroll
        for (int c = 0; c < 4; ++c) {  // component index static after unroll
            f32x4 acc = (f32x4)(0.f);
            #pragma unroll
            for (int r = 0; r < RANK; ++r) {
                float s = readlane_f32(aj[r][c], lane); // SGPR row value
                acc += s * aj[r];
            }
            const int i = rs * 64 + kb * 4 + c;
            if ((i >> 2) == cg) acc[i & 3] += lam; // diagonal
            __builtin_nontemporal_store(acc, op + (size_t)(kb * 4 + c) * (DIM / 4));
        }
    }
}

extern "C" void kernel_launch(void* const* d_in, const int* in_sizes, int n_in,
                              void* d_out, int out_size, void* d_ws, size_t ws_size,
                              hipStream_t stream) {
    const float* x          = (const float*)d_in[0];
    const float* A          = (const float*)d_in[1];
    const float* log_lambda = (const float*)d_in[2];
    const float* W          = (const float*)d_in[3];
    const float* bvec       = (const float*)d_in[4];
    float* out              = (float*)d_out;

    const int n_pos = in_sizes[0] / DIM; // B*S = 2048
    riemannian_metric_kernel<<<n_pos, 256, 0, stream>>>(x, A, log_lambda, W, bvec, out);
}